// Round 8
// baseline (56.189 us; speedup 1.0000x reference)
//
#include <hip/hip_runtime.h>
#include <hip/hip_fp16.h>

#define NN   2048
#define FIN  128
#define FOUT 64
#define LOG2E 1.44269504088896f

using f16x8 = __attribute__((ext_vector_type(8))) _Float16;
using f16x4 = __attribute__((ext_vector_type(4))) _Float16;
using f16x2 = __attribute__((ext_vector_type(2))) _Float16;
using f32x4 = __attribute__((ext_vector_type(4))) float;
using i32x4 = __attribute__((ext_vector_type(4))) int;

__device__ inline float fast_exp2(float x) {
#if __has_builtin(__builtin_amdgcn_exp2f)
    return __builtin_amdgcn_exp2f(x);
#else
    return exp2f(x);
#endif
}

// h16B frag-ordered layout, per (bh): halves offset =
//   bh*131072 + (j>>5)*2048 + (o>>4)*512 + (((j>>3)&3)*16 + (o&15))*8 + (j&7)
// adjbitsT layout: [b][wc(64)][row(2048)] uint32; bit q = adj[b][row][wc*32+q]

// ---------------------------------------------------------------------------
// Kernel 1: h = x @ w[h] (fp32) + tanh -> s_src/s_dst (log2e-scaled) + h->fp16
// frag order + adj bitpack (transposed). 512 blocks x 256 threads.
// ---------------------------------------------------------------------------
__global__ __launch_bounds__(256) void k1_proj(
    const float* __restrict__ x, const float* __restrict__ w,
    const float* __restrict__ a_src, const float* __restrict__ a_dst,
    const int* __restrict__ adj,
    _Float16* __restrict__ h16B, float* __restrict__ ssrc, float* __restrict__ sdst,
    unsigned int* __restrict__ adjbitsT)
{
    __shared__ __align__(16) float w_s[FIN * FOUT];
    __shared__ __align__(16) float xs[64 * 132];

    const int t    = threadIdx.x;
    const int bx   = blockIdx.x;
    const int bh   = bx >> 5;
    const int tile = bx & 31;
    const int b    = bh >> 2;
    const int h    = bh & 3;
    const int n0   = tile * 64;

    {
        const f32x4* wg = (const f32x4*)(w + h * FIN * FOUT);
        f32x4* wl = (f32x4*)w_s;
#pragma unroll
        for (int k = 0; k < 8; ++k) wl[t + 256 * k] = wg[t + 256 * k];
    }
    {
#pragma unroll
        for (int k = 0; k < 8; ++k) {
            int q  = t + 256 * k;
            int r  = q >> 5;
            int c4 = q & 31;
            f32x4 v = *(const f32x4*)(x + (size_t)(b * NN + n0 + r) * FIN + c4 * 4);
            *(f32x4*)(xs + r * 132 + c4 * 4) = v;
        }
    }
    __syncthreads();

    const int ty = t >> 4, tx = t & 15;
    float acc[4][4] = {};

#pragma unroll 4
    for (int f4 = 0; f4 < 32; ++f4) {
        f32x4 xv[4], wv[4];
#pragma unroll
        for (int q = 0; q < 4; ++q)
            xv[q] = *(const f32x4*)(xs + (ty * 4 + q) * 132 + f4 * 4);
#pragma unroll
        for (int k = 0; k < 4; ++k)
            wv[k] = *(const f32x4*)(w_s + (f4 * 4 + k) * 64 + tx * 4);
#pragma unroll
        for (int q = 0; q < 4; ++q)
#pragma unroll
            for (int k = 0; k < 4; ++k)
#pragma unroll
                for (int c = 0; c < 4; ++c)
                    acc[q][c] += xv[q][k] * wv[k][c];
    }

    const int j0 = n0 + ty * 4;
#pragma unroll
    for (int cc = 0; cc < 4; ++cc) {
        int o = tx * 4 + cc;
        f16x4 hv;
#pragma unroll
        for (int q = 0; q < 4; ++q) hv[q] = (_Float16)acc[q][cc];
        int off = bh * 131072 + (j0 >> 5) * 2048 + (o >> 4) * 512
                + (((j0 >> 3) & 3) * 16 + (o & 15)) * 8 + (j0 & 7);
        *(f16x4*)(h16B + off) = hv;
    }

    f32x4 a_s = *(const f32x4*)(a_src + h * FOUT + tx * 4);
    f32x4 a_d = *(const f32x4*)(a_dst + h * FOUT + tx * 4);
    float ss[4], sd[4];
#pragma unroll
    for (int q = 0; q < 4; ++q) {
        float s1 = 0.f, s2 = 0.f;
#pragma unroll
        for (int cc = 0; cc < 4; ++cc) {
            float th = tanhf(acc[q][cc]);
            s1 += th * a_s[cc];
            s2 += th * a_d[cc];
        }
        ss[q] = s1; sd[q] = s2;
    }
#pragma unroll
    for (int m = 1; m <= 8; m <<= 1) {
#pragma unroll
        for (int q = 0; q < 4; ++q) {
            ss[q] += __shfl_xor(ss[q], m);
            sd[q] += __shfl_xor(sd[q], m);
        }
    }
    if (tx == 0) {
#pragma unroll
        for (int q = 0; q < 4; ++q) {
            ssrc[bh * NN + j0 + q] = ss[q] * LOG2E;   // pre-scale: exp -> exp2
            sdst[bh * NN + j0 + q] = sd[q] * LOG2E;
        }
    }

    // ---- adj bitpack: block bx packs flat rows [bx*16, bx*16+16) ----
    {
        const int  frow0 = bx * 16;
        const int* asrc  = adj + (size_t)frow0 * NN;
#pragma unroll
        for (int w4 = 0; w4 < 4; ++w4) {
            int widx  = t + 256 * w4;          // 0..1023
            int row_l = widx >> 6;
            int wc    = widx & 63;
            const i32x4* p = (const i32x4*)(asrc + (size_t)row_l * NN + wc * 32);
            unsigned int wbits = 0;
#pragma unroll
            for (int k = 0; k < 8; ++k) {
                i32x4 v = p[k];
                wbits |= (unsigned int)(v[0] & 1) << (4 * k);
                wbits |= (unsigned int)(v[1] & 1) << (4 * k + 1);
                wbits |= (unsigned int)(v[2] & 1) << (4 * k + 2);
                wbits |= (unsigned int)(v[3] & 1) << (4 * k + 3);
            }
            int frow = frow0 + row_l;
            adjbitsT[(size_t)(frow >> 11) * 131072 + (size_t)wc * 2048 + (frow & 2047)] = wbits;
        }
    }
}

// ---------------------------------------------------------------------------
// Kernel 2: deep-pipelined masked-softmax attention + PV (T3/T4 structure).
// 512 blocks (16 bh x 32 tiles of 64 rows) x 512 threads (8 waves).
// 16 steps of 128 j. Triple-buffered 16KB B stages, prefetch distance 2,
// counted vmcnt(2) (never 0 until tail), ONE barrier per step.
// Wave (rg, par): rows rg*16.., j-half par of each step (2 sub-chunks of 32).
// ---------------------------------------------------------------------------
__global__ __launch_bounds__(512, 4) void k2_attn(
    const unsigned int* __restrict__ adjbitsT,
    const _Float16* __restrict__ h16B,
    const float* __restrict__ ssrc, const float* __restrict__ sdst,
    const float* __restrict__ bias, float* __restrict__ out)
{
    // smem: [0,48K) Bbuf 3x16KB | [48K,64K) adj words | [64K,72K) sd | +redmax
    // epilogue overlays comb (20KB) on [0,20K)
    __shared__ __align__(16) char smem[73792];
    _Float16*     Bf     = (_Float16*)smem;                 // 3 x 8192 halves
    unsigned int* adjw   = (unsigned int*)(smem + 49152);   // 4096 words
    float*        sd_lds = (float*)(smem + 65536);          // 2048 floats
    float*        redmax = (float*)(smem + 73728);
    float*        comb   = (float*)smem;

    const int t    = threadIdx.x;
    const int wv   = t >> 6;
    const int lane = t & 63;
    const int bh   = blockIdx.x >> 5;
    const int i0   = (blockIdx.x & 31) << 6;    // 64-row tile
    const int b    = bh >> 2;
    const int rg   = wv >> 1;
    const int par  = wv & 1;
    const int m    = lane & 15;
    const int g    = lane >> 4;

    const _Float16*     Bsrc = h16B + bh * 131072;
    const unsigned int* abT  = adjbitsT + (size_t)b * 131072;

#define STAGE(bufi_, s_) do {                                                       \
        const _Float16* gs_ = Bsrc + (s_) * 8192 + t * 8;                           \
        _Float16*       ld_ = Bf + (bufi_) * 8192 + t * 8;                          \
        __builtin_amdgcn_global_load_lds(                                           \
            (const __attribute__((address_space(1))) unsigned int*)gs_,             \
            (__attribute__((address_space(3))) unsigned int*)ld_, 16, 0, 0);        \
        __builtin_amdgcn_global_load_lds(                                           \
            (const __attribute__((address_space(1))) unsigned int*)(gs_ + 4096),    \
            (__attribute__((address_space(3))) unsigned int*)(ld_ + 4096), 16, 0, 0);\
    } while (0)

    // ---- prologue: adj words (16KB), sdst (8KB), B steps 0,1 ----
#pragma unroll
    for (int k = 0; k < 8; ++k) {
        int widx = t + 512 * k;                 // wc = widx>>6, row = widx&63
        __builtin_amdgcn_global_load_lds(
            (const __attribute__((address_space(1))) unsigned int*)(abT + (widx >> 6) * 2048 + i0 + (widx & 63)),
            (__attribute__((address_space(3))) unsigned int*)(adjw + widx), 4, 0, 0);
    }
#pragma unroll
    for (int k = 0; k < 4; ++k) {
        int widx = t + 512 * k;
        __builtin_amdgcn_global_load_lds(
            (const __attribute__((address_space(1))) unsigned int*)(sdst + bh * NN + widx),
            (__attribute__((address_space(3))) unsigned int*)(sd_lds + widx), 4, 0, 0);
    }
    STAGE(0, 0);
    STAGE(1, 1);
    asm volatile("s_waitcnt vmcnt(0)" ::: "memory");
    __syncthreads();

    // ---- D = max_j sdst ----
    float dm = -1e30f;
#pragma unroll
    for (int k = 0; k < 4; ++k) dm = fmaxf(dm, sd_lds[t + 512 * k]);
#pragma unroll
    for (int msk = 1; msk <= 32; msk <<= 1) dm = fmaxf(dm, __shfl_xor(dm, msk));
    if (lane == 0) redmax[wv] = dm;
    __syncthreads();
    float D = redmax[0];
#pragma unroll
    for (int k = 1; k < 8; ++k) D = fmaxf(D, redmax[k]);

    const int row = i0 + rg * 16 + m;
    const float sA = ssrc[bh * NN + row];
    float c = sA + D; c = fmaxf(c, 0.2f * c);    // leaky(sA+D) >= row max logit
    const float sAc  = sA - c;
    const float sAc2 = fmaf(0.2f, sA, -c);

    f32x4 acc0 = {0,0,0,0}, acc1 = {0,0,0,0}, acc2 = {0,0,0,0}, acc3 = {0,0,0,0};
    f32x4 accz = {0,0,0,0};
    f16x8 ones;
#pragma unroll
    for (int i = 0; i < 8; ++i) ones[i] = (_Float16)1.0f;

    int buf = 0;                   // = s % 3
    for (int s = 0; s < 16; ++s) {
        // prefetch distance 2: issue stage(s+2) first (flies across this step)
        if (s < 14) {
            int nb = buf + 2; if (nb >= 3) nb -= 3;
            STAGE(nb, s + 2);
        }

        // compute 2 sub-chunks (ci local = par*2, par*2+1) from buf
#pragma unroll
        for (int l = 0; l < 2; ++l) {
            const int cl  = par * 2 + l;            // 0..3 within step
            const int cig = s * 4 + cl;             // global word-col
            unsigned int wb = adjw[cig * 64 + rg * 16 + m] >> (8 * g);
            const float* djp = sd_lds + cig * 32 + 8 * g;
            f32x4 dj0 = *(const f32x4*)(djp);
            f32x4 dj1 = *(const f32x4*)(djp + 4);
            const _Float16* bb = Bf + buf * 8192 + cl * 2048 + lane * 8;
            f16x8 b0 = *(const f16x8*)(bb);
            f16x8 b1 = *(const f16x8*)(bb + 512);
            f16x8 b2 = *(const f16x8*)(bb + 1024);
            f16x8 b3 = *(const f16x8*)(bb + 1536);

            float ev[8];
#pragma unroll
            for (int i = 0; i < 8; ++i) {
                float dj = (i < 4) ? dj0[i] : dj1[i - 4];
                float a1 = sAc + dj;
                float a2 = fmaf(0.2f, dj, sAc2);
                float ee = fast_exp2(fmaxf(a1, a2));
                ev[i] = (wb & (1u << i)) ? ee : 0.0f;
            }
            union { f16x8 v; f16x2 p[4]; } af;
#pragma unroll
            for (int i = 0; i < 4; ++i)
                af.p[i] = __builtin_bit_cast(f16x2,
                    __builtin_amdgcn_cvt_pkrtz(ev[2 * i], ev[2 * i + 1]));

            acc0 = __builtin_amdgcn_mfma_f32_16x16x32_f16(af.v, b0, acc0, 0, 0, 0);
            acc1 = __builtin_amdgcn_mfma_f32_16x16x32_f16(af.v, b1, acc1, 0, 0, 0);
            acc2 = __builtin_amdgcn_mfma_f32_16x16x32_f16(af.v, b2, acc2, 0, 0, 0);
            acc3 = __builtin_amdgcn_mfma_f32_16x16x32_f16(af.v, b3, acc3, 0, 0, 0);
            accz = __builtin_amdgcn_mfma_f32_16x16x32_f16(af.v, ones, accz, 0, 0, 0);
        }

        // counted wait: stage(s+1) complete; stage(s+2) may stay in flight
        if (s < 14) {
            asm volatile("s_waitcnt vmcnt(2)" ::: "memory");
        } else {
            asm volatile("s_waitcnt vmcnt(0)" ::: "memory");
        }
        __builtin_amdgcn_sched_barrier(0);
        __builtin_amdgcn_s_barrier();
        __builtin_amdgcn_sched_barrier(0);

        ++buf; if (buf >= 3) buf -= 3;
    }
#undef STAGE

    // ---- combine parity partials (overlay comb on Bbuf region) ----
    __syncthreads();
    if (par == 1) {
        float* cp = comb + (rg * 64 + lane) * 20;
#pragma unroll
        for (int r = 0; r < 4; ++r) {
            cp[0 + r]  = acc0[r];
            cp[4 + r]  = acc1[r];
            cp[8 + r]  = acc2[r];
            cp[12 + r] = acc3[r];
            cp[16 + r] = accz[r];
        }
    }
    __syncthreads();
    if (par == 0) {
        const float* cp = comb + (rg * 64 + lane) * 20;
        float zs[4];
#pragma unroll
        for (int r = 0; r < 4; ++r) zs[r] = accz[r] + cp[16 + r];
        size_t obase = ((size_t)bh * NN + i0 + rg * 16) * FOUT;
        // C/D layout: col = lane&15, row = g*4 + r
#pragma unroll
        for (int ot = 0; ot < 4; ++ot) {
            float bv = bias[ot * 16 + m];
            f32x4 a = (ot == 0) ? acc0 : (ot == 1) ? acc1 : (ot == 2) ? acc2 : acc3;
#pragma unroll
            for (int r = 0; r < 4; ++r) {
                float v = (a[r] + cp[ot * 4 + r]) / zs[r] + bv;
                out[obase + (size_t)(g * 4 + r) * FOUT + ot * 16 + m] = v;
            }
        }
    }
}

// ---------------------------------------------------------------------------
extern "C" void kernel_launch(void* const* d_in, const int* in_sizes, int n_in,
                              void* d_out, int out_size, void* d_ws, size_t ws_size,
                              hipStream_t stream) {
    (void)in_sizes; (void)n_in; (void)out_size; (void)ws_size;
    const float* x     = (const float*)d_in[0];
    const int*   adj   = (const int*)d_in[1];     // bool -> int32
    const float* w     = (const float*)d_in[2];
    const float* a_src = (const float*)d_in[3];
    const float* a_dst = (const float*)d_in[4];
    const float* bias  = (const float*)d_in[5];
    float*       out   = (float*)d_out;

    _Float16*     h16B  = (_Float16*)d_ws;                               // 4 MB
    float*        ssrc  = (float*)((char*)d_ws + 4194304);               // 128 KB
    float*        sdst  = (float*)((char*)d_ws + 4194304 + 131072);      // 128 KB
    unsigned int* abT   = (unsigned int*)((char*)d_ws + 4718592);        // 2 MB

    k1_proj<<<512, 256, 0, stream>>>(x, w, a_src, a_dst, adj, h16B, ssrc, sdst, abT);
    k2_attn<<<512, 512, 0, stream>>>(abT, h16B, ssrc, sdst, bias, out);
}

// Round 9
// 50.581 us; speedup vs baseline: 1.1109x; 1.1109x over previous
//
#include <hip/hip_runtime.h>
#include <hip/hip_fp16.h>

#define NN   2048
#define FIN  128
#define FOUT 64
#define LOG2E 1.44269504088896f

using f16x8 = __attribute__((ext_vector_type(8))) _Float16;
using f16x4 = __attribute__((ext_vector_type(4))) _Float16;
using f16x2 = __attribute__((ext_vector_type(2))) _Float16;
using f32x4 = __attribute__((ext_vector_type(4))) float;
using i32x4 = __attribute__((ext_vector_type(4))) int;

__device__ inline float fast_exp2(float x) {
#if __has_builtin(__builtin_amdgcn_exp2f)
    return __builtin_amdgcn_exp2f(x);
#else
    return exp2f(x);
#endif
}

// h16B frag-ordered layout, per (bh): halves offset =
//   bh*131072 + (j>>5)*2048 + (o>>4)*512 + (((j>>3)&3)*16 + (o&15))*8 + (j&7)
// adjbits layout (ROW-MAJOR, dense): [flat_row(8192)][wc(64)] u32;
//   bit q of word = adj[row][wc*32+q]

// ---------------------------------------------------------------------------
// Kernel 1: h = x @ w[h] (fp32) + tanh -> s_src/s_dst (log2e-scaled) + h->fp16
// frag order + adj bitpack (dense row-major). 512 blocks x 256 threads.
// ---------------------------------------------------------------------------
__global__ __launch_bounds__(256) void k1_proj(
    const float* __restrict__ x, const float* __restrict__ w,
    const float* __restrict__ a_src, const float* __restrict__ a_dst,
    const int* __restrict__ adj,
    _Float16* __restrict__ h16B, float* __restrict__ ssrc, float* __restrict__ sdst,
    unsigned int* __restrict__ adjbits)
{
    __shared__ __align__(16) float w_s[FIN * FOUT];
    __shared__ __align__(16) float xs[64 * 132];

    const int t    = threadIdx.x;
    const int bx   = blockIdx.x;
    const int bh   = bx >> 5;
    const int tile = bx & 31;
    const int b    = bh >> 2;
    const int h    = bh & 3;
    const int n0   = tile * 64;

    {
        const f32x4* wg = (const f32x4*)(w + h * FIN * FOUT);
        f32x4* wl = (f32x4*)w_s;
#pragma unroll
        for (int k = 0; k < 8; ++k) wl[t + 256 * k] = wg[t + 256 * k];
    }
    {
#pragma unroll
        for (int k = 0; k < 8; ++k) {
            int q  = t + 256 * k;
            int r  = q >> 5;
            int c4 = q & 31;
            f32x4 v = *(const f32x4*)(x + (size_t)(b * NN + n0 + r) * FIN + c4 * 4);
            *(f32x4*)(xs + r * 132 + c4 * 4) = v;
        }
    }
    __syncthreads();

    const int ty = t >> 4, tx = t & 15;
    float acc[4][4] = {};

#pragma unroll 4
    for (int f4 = 0; f4 < 32; ++f4) {
        f32x4 xv[4], wv[4];
#pragma unroll
        for (int q = 0; q < 4; ++q)
            xv[q] = *(const f32x4*)(xs + (ty * 4 + q) * 132 + f4 * 4);
#pragma unroll
        for (int k = 0; k < 4; ++k)
            wv[k] = *(const f32x4*)(w_s + (f4 * 4 + k) * 64 + tx * 4);
#pragma unroll
        for (int q = 0; q < 4; ++q)
#pragma unroll
            for (int k = 0; k < 4; ++k)
#pragma unroll
                for (int c = 0; c < 4; ++c)
                    acc[q][c] += xv[q][k] * wv[k][c];
    }

    const int j0 = n0 + ty * 4;
#pragma unroll
    for (int cc = 0; cc < 4; ++cc) {
        int o = tx * 4 + cc;
        f16x4 hv;
#pragma unroll
        for (int q = 0; q < 4; ++q) hv[q] = (_Float16)acc[q][cc];
        int off = bh * 131072 + (j0 >> 5) * 2048 + (o >> 4) * 512
                + (((j0 >> 3) & 3) * 16 + (o & 15)) * 8 + (j0 & 7);
        *(f16x4*)(h16B + off) = hv;
    }

    f32x4 a_s = *(const f32x4*)(a_src + h * FOUT + tx * 4);
    f32x4 a_d = *(const f32x4*)(a_dst + h * FOUT + tx * 4);
    float ss[4], sd[4];
#pragma unroll
    for (int q = 0; q < 4; ++q) {
        float s1 = 0.f, s2 = 0.f;
#pragma unroll
        for (int cc = 0; cc < 4; ++cc) {
            float th = tanhf(acc[q][cc]);
            s1 += th * a_s[cc];
            s2 += th * a_d[cc];
        }
        ss[q] = s1; sd[q] = s2;
    }
#pragma unroll
    for (int m = 1; m <= 8; m <<= 1) {
#pragma unroll
        for (int q = 0; q < 4; ++q) {
            ss[q] += __shfl_xor(ss[q], m);
            sd[q] += __shfl_xor(sd[q], m);
        }
    }
    if (tx == 0) {
#pragma unroll
        for (int q = 0; q < 4; ++q) {
            ssrc[bh * NN + j0 + q] = ss[q] * LOG2E;   // pre-scale: exp -> exp2
            sdst[bh * NN + j0 + q] = sd[q] * LOG2E;
        }
    }

    // ---- adj bitpack: block bx packs flat rows [bx*16, bx*16+16), DENSE store ----
    {
        const int  frow0 = bx * 16;
        const int* asrc  = adj + (size_t)frow0 * NN;
#pragma unroll
        for (int w4 = 0; w4 < 4; ++w4) {
            int widx  = t + 256 * w4;          // 0..1023
            int row_l = widx >> 6;
            int wc    = widx & 63;
            const i32x4* p = (const i32x4*)(asrc + (size_t)row_l * NN + wc * 32);
            unsigned int wbits = 0;
#pragma unroll
            for (int k = 0; k < 8; ++k) {
                i32x4 v = p[k];
                wbits |= (unsigned int)(v[0] & 1) << (4 * k);
                wbits |= (unsigned int)(v[1] & 1) << (4 * k + 1);
                wbits |= (unsigned int)(v[2] & 1) << (4 * k + 2);
                wbits |= (unsigned int)(v[3] & 1) << (4 * k + 3);
            }
            // dense row-major: consecutive lanes -> consecutive words (coalesced)
            adjbits[(size_t)(frow0 + row_l) * 64 + wc] = wbits;
        }
    }
}

// ---------------------------------------------------------------------------
// Kernel 2: masked-softmax attention + PV (fp16 MFMA), E-table e-gen.
// 512 blocks (16 bh x 32 tiles of 64 rows) x 512 threads (8 waves).
// Per 64-j step: dbuf B stage (global_load_lds, vmcnt(1)) | e-gen =
// mask ? max(K1*E1[j], K2*E2[j]) : 0 (NO exp in loop) | 5 MFMAs | 2 barriers.
// adj bits LDS-resident (row-major, pad-68 stride); E1/E2 LDS tables.
// LDS ~49 KB -> 3 blocks/CU (24 waves).
// ---------------------------------------------------------------------------
__global__ __launch_bounds__(512, 6) void k2_attn(
    const unsigned int* __restrict__ adjbits,
    const _Float16* __restrict__ h16B,
    const float* __restrict__ ssrc, const float* __restrict__ sdst,
    const float* __restrict__ bias, float* __restrict__ out)
{
    // smem: [0,16K) Bbuf 2x8KB | [16384,+17408) adjw 64x68 | [33792,+8K) E1 |
    //       [41984,+8K) E2 | [50176,+64) redmax.  comb (20KB) overlays [0,20K).
    __shared__ __align__(16) char smem[50240];
    _Float16*     Bf     = (_Float16*)smem;
    unsigned int* adjw   = (unsigned int*)(smem + 16384);  // stride 68 words
    float*        E1f    = (float*)(smem + 33792);
    float*        E2f    = (float*)(smem + 41984);
    float*        redmax = (float*)(smem + 50176);
    float*        comb   = (float*)smem;

    const int t    = threadIdx.x;
    const int wv   = t >> 6;
    const int lane = t & 63;
    const int bh   = blockIdx.x >> 5;
    const int i0   = (blockIdx.x & 31) << 6;    // 64-row tile
    const int b    = bh >> 2;
    const int rg   = wv >> 1;
    const int par  = wv & 1;
    const int m    = lane & 15;
    const int g    = lane >> 4;

    const _Float16* Bsrc = h16B + bh * 131072;

#define STAGE(bufi_, s_)                                                        \
    __builtin_amdgcn_global_load_lds(                                           \
        (const __attribute__((address_space(1))) unsigned int*)(Bsrc + (s_) * 4096 + t * 8), \
        (__attribute__((address_space(3))) unsigned int*)(Bf + (bufi_) * 4096 + t * 8), \
        16, 0, 0)

    // ---- prologue ----
    STAGE(0, 0);                                   // B step 0 flies during setup

    // adj slab: 16 KB contiguous -> reg-stage into padded (stride 68) LDS
    {
        const uint4* asrc = (const uint4*)(adjbits + ((size_t)b * NN + i0) * 64);
#pragma unroll
        for (int k = 0; k < 2; ++k) {
            int idx = t + 512 * k;                 // 0..1023; row = idx>>4
            uint4 v = asrc[idx];
            unsigned int* dst = adjw + (idx >> 4) * 68 + (idx & 15) * 4;
            *(uint4*)dst = v;
        }
    }
    // E tables + D-max
    float dm;
    {
        f32x4 dv = *(const f32x4*)(sdst + bh * NN + t * 4);
        f32x4 e1v, e2v;
#pragma unroll
        for (int e = 0; e < 4; ++e) {
            e1v[e] = fast_exp2(dv[e]);
            e2v[e] = fast_exp2(0.2f * dv[e]);
        }
        *(f32x4*)(E1f + t * 4) = e1v;
        *(f32x4*)(E2f + t * 4) = e2v;
        dm = fmaxf(fmaxf(dv[0], dv[1]), fmaxf(dv[2], dv[3]));
#pragma unroll
        for (int msk = 1; msk <= 32; msk <<= 1) dm = fmaxf(dm, __shfl_xor(dm, msk));
        if (lane == 0) redmax[wv] = dm;
    }
    asm volatile("s_waitcnt vmcnt(0)" ::: "memory");   // B step 0 + adj loads done
    __syncthreads();

    float D = redmax[0];
#pragma unroll
    for (int k = 1; k < 8; ++k) D = fmaxf(D, redmax[k]);

    const int row = i0 + rg * 16 + m;
    const float sA = ssrc[bh * NN + row];
    float c = sA + D; c = fmaxf(c, 0.2f * c);    // leaky(sA+D) >= row max logit
    const float K1 = fast_exp2(sA - c);          // e = max(K1*E1[j], K2*E2[j])
    const float K2 = fast_exp2(fmaf(0.2f, sA, -c));

    f32x4 acc0 = {0,0,0,0}, acc1 = {0,0,0,0}, acc2 = {0,0,0,0}, acc3 = {0,0,0,0};
    f32x4 accz = {0,0,0,0};
    f16x8 ones;
#pragma unroll
    for (int i = 0; i < 8; ++i) ones[i] = (_Float16)1.0f;

    const int arow68 = (rg * 16 + m) * 68;

    for (int s = 0; s < 32; ++s) {
        if (s < 31) {
            STAGE((s + 1) & 1, s + 1);
            asm volatile("s_waitcnt vmcnt(1)" ::: "memory");  // stage(s) done
        } else {
            asm volatile("s_waitcnt vmcnt(0)" ::: "memory");
        }
        __builtin_amdgcn_sched_barrier(0);
        __builtin_amdgcn_s_barrier();
        __builtin_amdgcn_sched_barrier(0);

        const int ci = 2 * s + par;                 // 32-j word-col
        unsigned int wb = adjw[arow68 + ci] >> (8 * g);
        const float* e1p = E1f + ci * 32 + 8 * g;
        const float* e2p = E2f + ci * 32 + 8 * g;
        f32x4 e1a = *(const f32x4*)(e1p);
        f32x4 e1b = *(const f32x4*)(e1p + 4);
        f32x4 e2a = *(const f32x4*)(e2p);
        f32x4 e2b = *(const f32x4*)(e2p + 4);

        const _Float16* bb = Bf + (s & 1) * 4096 + par * 2048 + lane * 8;
        f16x8 b0 = *(const f16x8*)(bb);
        f16x8 b1 = *(const f16x8*)(bb + 512);
        f16x8 b2 = *(const f16x8*)(bb + 1024);
        f16x8 b3 = *(const f16x8*)(bb + 1536);

        float ev[8];
#pragma unroll
        for (int i = 0; i < 8; ++i) {
            float E1v = (i < 4) ? e1a[i] : e1b[i - 4];
            float E2v = (i < 4) ? e2a[i] : e2b[i - 4];
            float ee  = fmaxf(K1 * E1v, K2 * E2v);
            ev[i] = (wb & (1u << i)) ? ee : 0.0f;
        }
        union { f16x8 v; f16x2 p[4]; } af;
#pragma unroll
        for (int i = 0; i < 4; ++i)
            af.p[i] = __builtin_bit_cast(f16x2,
                __builtin_amdgcn_cvt_pkrtz(ev[2 * i], ev[2 * i + 1]));

        acc0 = __builtin_amdgcn_mfma_f32_16x16x32_f16(af.v, b0, acc0, 0, 0, 0);
        acc1 = __builtin_amdgcn_mfma_f32_16x16x32_f16(af.v, b1, acc1, 0, 0, 0);
        acc2 = __builtin_amdgcn_mfma_f32_16x16x32_f16(af.v, b2, acc2, 0, 0, 0);
        acc3 = __builtin_amdgcn_mfma_f32_16x16x32_f16(af.v, b3, acc3, 0, 0, 0);
        accz = __builtin_amdgcn_mfma_f32_16x16x32_f16(af.v, ones, accz, 0, 0, 0);

        __builtin_amdgcn_s_barrier();   // protect buf before next-iter overwrite
    }
#undef STAGE

    // ---- combine parity partials (overlay comb on Bbuf/adjw region) ----
    __syncthreads();
    if (par == 1) {
        float* cp = comb + (rg * 64 + lane) * 20;
#pragma unroll
        for (int r = 0; r < 4; ++r) {
            cp[0 + r]  = acc0[r];
            cp[4 + r]  = acc1[r];
            cp[8 + r]  = acc2[r];
            cp[12 + r] = acc3[r];
            cp[16 + r] = accz[r];
        }
    }
    __syncthreads();
    if (par == 0) {
        const float* cp = comb + (rg * 64 + lane) * 20;
        float zs[4];
#pragma unroll
        for (int r = 0; r < 4; ++r) zs[r] = accz[r] + cp[16 + r];
        size_t obase = ((size_t)bh * NN + i0 + rg * 16) * FOUT;
        // C/D layout: col = lane&15, row = g*4 + r
#pragma unroll
        for (int ot = 0; ot < 4; ++ot) {
            float bv = bias[ot * 16 + m];
            f32x4 a = (ot == 0) ? acc0 : (ot == 1) ? acc1 : (ot == 2) ? acc2 : acc3;
#pragma unroll
            for (int r = 0; r < 4; ++r) {
                float v = (a[r] + cp[ot * 4 + r]) / zs[r] + bv;
                out[obase + (size_t)(g * 4 + r) * FOUT + ot * 16 + m] = v;
            }
        }
    }
}

// ---------------------------------------------------------------------------
extern "C" void kernel_launch(void* const* d_in, const int* in_sizes, int n_in,
                              void* d_out, int out_size, void* d_ws, size_t ws_size,
                              hipStream_t stream) {
    (void)in_sizes; (void)n_in; (void)out_size; (void)ws_size;
    const float* x     = (const float*)d_in[0];
    const int*   adj   = (const int*)d_in[1];     // bool -> int32
    const float* w     = (const float*)d_in[2];
    const float* a_src = (const float*)d_in[3];
    const float* a_dst = (const float*)d_in[4];
    const float* bias  = (const float*)d_in[5];
    float*       out   = (float*)d_out;

    _Float16*     h16B    = (_Float16*)d_ws;                               // 4 MB
    float*        ssrc    = (float*)((char*)d_ws + 4194304);               // 128 KB
    float*        sdst    = (float*)((char*)d_ws + 4194304 + 131072);      // 128 KB
    unsigned int* adjbits = (unsigned int*)((char*)d_ws + 4718592);        // 2 MB

    k1_proj<<<512, 256, 0, stream>>>(x, w, a_src, a_dst, adj, h16B, ssrc, sdst, adjbits);
    k2_attn<<<512, 512, 0, stream>>>(adjbits, h16B, ssrc, sdst, bias, out);
}